// Round 13
// baseline (629.251 us; speedup 1.0000x reference)
//
#include <hip/hip_runtime.h>
#include <hip/hip_bf16.h>

#define HH   128
#define EMB  300
#define SEQ  1024
#define BS   64
#define NG   384   // 3*H
#define NCHUNK 8   // col_sum t-chunks

typedef __attribute__((ext_vector_type(8))) short  bf16x8;
typedef __attribute__((ext_vector_type(4))) float  f32x4;
typedef _Float16 f16x2 __attribute__((ext_vector_type(2)));

__device__ __forceinline__ unsigned short f2bf(float f) {
    unsigned int u = __float_as_uint(f);
    unsigned int r = (u + 0x7fffu + ((u >> 16) & 1u)) >> 16;   // RNE
    return (unsigned short)r;
}
__device__ __forceinline__ float fexp(float x) { return __builtin_amdgcn_exp2f(x * 1.44269504088896f); }
__device__ __forceinline__ float fsig(float x) { return __builtin_amdgcn_rcpf(1.f + fexp(-x)); }
__device__ __forceinline__ float ftanh(float x){ return __builtin_amdgcn_rcpf(1.f + fexp(-2.f*x)) * 2.f - 1.f; }

// fused packed f16 FMA: d = a*b + c in ONE VOP3P instruction (the compiler
// refuses to fuse f16x2 mul+add into v_pk_fma_f16 on its own -> r12's loss).
__device__ __forceinline__ f16x2 pk_fma(f16x2 a, f16x2 b, f16x2 c) {
    f16x2 d;
    asm("v_pk_fma_f16 %0, %1, %2, %3" : "=v"(d) : "v"(a), "v"(b), "v"(c));
    return d;
}

// add the value from the adjacent lane (lane^1) via DPP quad_perm(1,0,3,2)
__device__ __forceinline__ float dpp_pair_add(float x) {
    int y = __builtin_amdgcn_mov_dpp(__float_as_int(x), 0xB1, 0xF, 0xF, true);
    return x + __int_as_float(y);
}

// LDS-only barrier: drains LDS ops but leaves global loads in flight.
#define BAR_LDS() asm volatile("s_waitcnt lgkmcnt(0)\n\ts_barrier" ::: "memory")

// ---------------------------------------------------------------------------
// gi[r, j] = (sum_e X[r,e]*mask[r]*W[j,e]) + bias[j] + (j<2H ? bhh[j] : 0)
// Single X pass: block = 128 M-rows x FULL N=384, 512 threads (8 waves 2m x 4n).
// ---------------------------------------------------------------------------
__global__ __launch_bounds__(512) void gi_gemm(const float* __restrict__ X,
                                               const float* __restrict__ mask,
                                               const float* __restrict__ W,
                                               const float* __restrict__ bias,
                                               const float* __restrict__ bhh2,
                                               float* __restrict__ out) {
    __shared__ __align__(16) unsigned short As[128 * 32];
    __shared__ __align__(16) unsigned short Bs[384 * 32];
    const int m0   = blockIdx.x * 128;
    const int tid  = threadIdx.x;
    const int row  = tid >> 2;            // 0..127
    const int seg  = tid & 3;             // 8-col segment
    const int wave = tid >> 6;            // 0..7
    const int lane = tid & 63;
    const int wm   = wave >> 2;           // 0..1 (64 M rows each)
    const int wn   = wave & 3;            // 0..3 (96 N cols each)
    const int r16  = lane & 15, kg = lane >> 4;

    f32x4 acc[4][6];
    #pragma unroll
    for (int m = 0; m < 4; ++m)
        #pragma unroll
        for (int n = 0; n < 6; ++n) acc[m][n] = (f32x4){0.f,0.f,0.f,0.f};

    const float mrow = mask[m0 + row];

    for (int k0 = 0; k0 < 320; k0 += 32) {
        // ---- stage A (x * mask -> bf16), 8 cols per thread ----
        {
            const float* src = X + (size_t)(m0 + row) * EMB + k0 + seg * 8;
            unsigned short tmp[8];
            if (k0 + seg * 8 + 7 < EMB) {
                float4 v0 = ((const float4*)src)[0];
                float4 v1 = ((const float4*)src)[1];
                tmp[0]=f2bf(v0.x*mrow); tmp[1]=f2bf(v0.y*mrow);
                tmp[2]=f2bf(v0.z*mrow); tmp[3]=f2bf(v0.w*mrow);
                tmp[4]=f2bf(v1.x*mrow); tmp[5]=f2bf(v1.y*mrow);
                tmp[6]=f2bf(v1.z*mrow); tmp[7]=f2bf(v1.w*mrow);
            } else {
                #pragma unroll
                for (int i = 0; i < 8; ++i) {
                    int c = k0 + seg * 8 + i;
                    float v = (c < EMB) ? src[i] : 0.f;
                    tmp[i] = f2bf(v * mrow);
                }
            }
            *(uint4*)&As[row * 32 + seg * 8] = *(const uint4*)tmp;
        }
        // ---- stage B (W -> bf16): 3 row-groups per thread ----
        #pragma unroll
        for (int r3 = 0; r3 < 3; ++r3) {
            const int rowb = row + r3 * 128;
            const float* src = W + (size_t)rowb * EMB + k0 + seg * 8;
            unsigned short tmp[8];
            if (k0 + seg * 8 + 7 < EMB) {
                float4 v0 = ((const float4*)src)[0];
                float4 v1 = ((const float4*)src)[1];
                tmp[0]=f2bf(v0.x); tmp[1]=f2bf(v0.y); tmp[2]=f2bf(v0.z); tmp[3]=f2bf(v0.w);
                tmp[4]=f2bf(v1.x); tmp[5]=f2bf(v1.y); tmp[6]=f2bf(v1.z); tmp[7]=f2bf(v1.w);
            } else {
                #pragma unroll
                for (int i = 0; i < 8; ++i) {
                    int c = k0 + seg * 8 + i;
                    float v = (c < EMB) ? src[i] : 0.f;
                    tmp[i] = f2bf(v);
                }
            }
            *(uint4*)&Bs[rowb * 32 + seg * 8] = *(const uint4*)tmp;
        }
        __syncthreads();

        bf16x8 a[4], bfr[6];
        #pragma unroll
        for (int m = 0; m < 4; ++m)
            a[m] = *(const bf16x8*)&As[(wm * 64 + m * 16 + r16) * 32 + kg * 8];
        #pragma unroll
        for (int n = 0; n < 6; ++n)
            bfr[n] = *(const bf16x8*)&Bs[(wn * 96 + n * 16 + r16) * 32 + kg * 8];
        #pragma unroll
        for (int m = 0; m < 4; ++m)
            #pragma unroll
            for (int n = 0; n < 6; ++n)
                acc[m][n] = __builtin_amdgcn_mfma_f32_16x16x32_bf16(a[m], bfr[n], acc[m][n], 0, 0, 0);
        __syncthreads();
    }

    // ---- epilogue: f32 gi with r/z recurrent bias folded ----
    #pragma unroll
    for (int m = 0; m < 4; ++m) {
        const int rowb = m0 + wm * 64 + m * 16 + kg * 4;
        #pragma unroll
        for (int n = 0; n < 6; ++n) {
            const int col = wn * 96 + n * 16 + r16;
            const float bj = bias[col] + (col < 2 * HH ? bhh2[col] : 0.f);
            #pragma unroll
            for (int q = 0; q < 4; ++q)
                out[(size_t)(rowb + q) * NG + col] = acc[m][n][q] + bj;
        }
    }
}

// ---------------------------------------------------------------------------
// partial column sums: spart[(b*NCHUNK + c)][e] = sum over 128 t's
// ---------------------------------------------------------------------------
__global__ __launch_bounds__(320) void col_sum(const float* __restrict__ X,
                                               const float* __restrict__ mask,
                                               float* __restrict__ spart) {
    const int b = blockIdx.x, c = blockIdx.y;
    const int e = threadIdx.x;
    if (e >= EMB) return;
    const int tchunk = SEQ / NCHUNK;   // 128
    float acc = 0.f;
    const float* xb = X + ((size_t)b * SEQ + (size_t)c * tchunk) * EMB;
    const float* mb = mask + (size_t)b * SEQ + (size_t)c * tchunk;
    for (int t = 0; t < tchunk; ++t)
        acc += xb[(size_t)t * EMB + e] * mb[t];
    spart[((size_t)b * NCHUNK + c) * EMB + e] = acc;
}

// ---------------------------------------------------------------------------
// forward GRU scan (r6 structure, fused v_pk_fma_f16 dots): 256 threads,
// 64 blocks. Output j = tid>>1, k-half = tid&1 (adjacent lanes, DPP pair-add
// combine). Dots = 96 single-instruction packed FMAs per lane on 4
// independent f16x2 chains per gate. One barrier per step (double-buffered
// f16 h). gi f32 with r/z biases pre-folded; prefetched 4 steps ahead via
// incremental pointers; BAR_LDS keeps those loads in flight.
// ---------------------------------------------------------------------------
__global__ __launch_bounds__(256, 1) void gru_scan(const float* __restrict__ gi,
                                                   const float* __restrict__ Whh,
                                                   const float* __restrict__ bhh,
                                                   float* __restrict__ hout) {
    const int b    = blockIdx.x;
    const int tid  = threadIdx.x;
    const int j    = tid >> 1;           // 0..127 output index
    const int half = tid & 1;            // k-half (adjacent lanes)
    __shared__ __align__(16) _Float16 hb[2][HH];

    // ---- weights: rows j, j+HH, j+2HH, cols [half*64, half*64+64) ----
    f16x2 wr_[32], wz_[32], wn_[32];
    {
        const float2* r0 = (const float2*)(Whh + (size_t)j * HH            + half * 64);
        const float2* r1 = (const float2*)(Whh + (size_t)(j + HH) * HH     + half * 64);
        const float2* r2 = (const float2*)(Whh + (size_t)(j + 2 * HH) * HH + half * 64);
        #pragma unroll
        for (int i = 0; i < 32; ++i) {
            float2 a = r0[i], c = r1[i], d = r2[i];
            wr_[i] = (f16x2){(_Float16)a.x, (_Float16)a.y};
            wz_[i] = (f16x2){(_Float16)c.x, (_Float16)c.y};
            wn_[i] = (f16x2){(_Float16)d.x, (_Float16)d.y};
        }
    }
    const float bn_ = bhh[j + 2 * HH];   // r/z biases folded into gi

    float hreg = 0.f;
    if (tid < HH) hb[0][tid] = (_Float16)0.f;
    const float* gb = gi + (size_t)b * SEQ * NG;

    // depth-4 prefetch registers + incremental source pointers
    float gAr, gAz, gAn, gBr, gBz, gBn, gCr, gCz, gCn, gDr, gDz, gDn;
    {
        const float* g0 = gb;               gAr = g0[j]; gAz = g0[j+HH]; gAn = g0[j+2*HH];
        const float* g1 = gb + NG;          gBr = g1[j]; gBz = g1[j+HH]; gBn = g1[j+2*HH];
        const float* g2 = gb + 2 * NG;      gCr = g2[j]; gCz = g2[j+HH]; gCn = g2[j+2*HH];
        const float* g3 = gb + 3 * NG;      gDr = g3[j]; gDz = g3[j+HH]; gDn = g3[j+2*HH];
    }
    const float* pA = gb + 4 * NG;
    const float* pB = gb + 5 * NG;
    const float* pC = gb + 6 * NG;
    const float* pD = gb + 7 * NG;
    BAR_LDS();

    const f16x2 Z2 = (f16x2){(_Float16)0.f, (_Float16)0.f};

    // NOTE: prefetch in the final iterations reads past gi's end into the
    // spart/hf scratch regions (allocated) — loaded but never consumed.
#define GRU_BODY(P, GR, GZ, GN, PP)                                            \
    {                                                                          \
        f16x2 ar0=Z2, ar1=Z2, ar2=Z2, ar3=Z2;                                  \
        f16x2 az0=Z2, az1=Z2, az2=Z2, az3=Z2;                                  \
        f16x2 an0=Z2, an1=Z2, an2=Z2, an3=Z2;                                  \
        const uint4* hp = (const uint4*)&hb[P][half * 64];                     \
        _Pragma("unroll")                                                      \
        for (int i = 0; i < 8; ++i) {                                          \
            union { uint4 u; f16x2 h2[4]; } U;                                 \
            U.u = hp[i];                                                       \
            ar0 = pk_fma(wr_[i*4+0], U.h2[0], ar0);                            \
            ar1 = pk_fma(wr_[i*4+1], U.h2[1], ar1);                            \
            ar2 = pk_fma(wr_[i*4+2], U.h2[2], ar2);                            \
            ar3 = pk_fma(wr_[i*4+3], U.h2[3], ar3);                            \
            az0 = pk_fma(wz_[i*4+0], U.h2[0], az0);                            \
            az1 = pk_fma(wz_[i*4+1], U.h2[1], az1);                            \
            az2 = pk_fma(wz_[i*4+2], U.h2[2], az2);                            \
            az3 = pk_fma(wz_[i*4+3], U.h2[3], az3);                            \
            an0 = pk_fma(wn_[i*4+0], U.h2[0], an0);                            \
            an1 = pk_fma(wn_[i*4+1], U.h2[1], an1);                            \
            an2 = pk_fma(wn_[i*4+2], U.h2[2], an2);                            \
            an3 = pk_fma(wn_[i*4+3], U.h2[3], an3);                            \
        }                                                                      \
        f16x2 sr = (ar0 + ar1) + (ar2 + ar3);                                  \
        f16x2 sz = (az0 + az1) + (az2 + az3);                                  \
        f16x2 sn = (an0 + an1) + (an2 + an3);                                  \
        const float arf = dpp_pair_add((float)sr[0] + (float)sr[1]);           \
        const float azf = dpp_pair_add((float)sz[0] + (float)sz[1]);           \
        const float anf = dpp_pair_add((float)sn[0] + (float)sn[1]);           \
        const float r = fsig(GR + arf);                                        \
        const float z = fsig(GZ + azf);                                        \
        const float n = ftanh(GN + r * (anf + bn_));                           \
        hreg = n + z * (hreg - n);                                             \
        if (!half) hb[P ^ 1][j] = (_Float16)hreg;                              \
        GR = PP[j]; GZ = PP[j + HH]; GN = PP[j + 2 * HH];                      \
        PP += 4 * NG;                                                          \
        BAR_LDS();                                                             \
    }

    for (int it = 0; it < SEQ / 4; ++it) {
        GRU_BODY(0, gAr, gAz, gAn, pA)
        GRU_BODY(1, gBr, gBz, gBn, pB)
        GRU_BODY(0, gCr, gCz, gCn, pC)
        GRU_BODY(1, gDr, gDz, gDn, pD)
    }
#undef GRU_BODY
    if (!half) hout[b * HH + j] = hreg;
}

// ---------------------------------------------------------------------------
// fused backward-direction GRU cell + MLP head.
// ---------------------------------------------------------------------------
__global__ __launch_bounds__(128) void mlp(const float* __restrict__ X,
                                           const float* __restrict__ mask,
                                           const float* __restrict__ WihB,
                                           const float* __restrict__ bihB,
                                           const float* __restrict__ bhhB,
                                           const float* __restrict__ hf,
                                           const float* __restrict__ spart,
                                           const float* __restrict__ W1, const float* __restrict__ b1,
                                           const float* __restrict__ W2, const float* __restrict__ b2,
                                           const float* __restrict__ W3, const float* __restrict__ b3,
                                           float* __restrict__ out) {
    const int b = blockIdx.x, j = threadIdx.x;
    __shared__ float xl[EMB];
    __shared__ float zin[2 * HH + EMB];   // 556
    __shared__ float l1[128];
    __shared__ float l2[64];

    const float* xr = X + ((size_t)b * SEQ + (SEQ - 1)) * EMB;
    const float  mv = mask[(size_t)b * SEQ + SEQ - 1];
    for (int e = j; e < EMB; e += 128) xl[e] = xr[e];
    zin[j] = hf[b * HH + j];
    for (int e = j; e < EMB; e += 128) {
        float v = 0.f;
        #pragma unroll
        for (int c = 0; c < NCHUNK; ++c)
            v += spart[((size_t)b * NCHUNK + c) * EMB + e];
        zin[2 * HH + e] = v * v;
    }
    __syncthreads();

    // ---- h_bwd[j]: one GRU cell on last token, h0 = 0 ----
    {
        const float* wR = WihB + (size_t)j * EMB;
        const float* wZ = WihB + (size_t)(j + HH) * EMB;
        const float* wN = WihB + (size_t)(j + 2 * HH) * EMB;
        float aR = 0.f, aZ = 0.f, aN = 0.f;
        for (int e = 0; e < EMB; ++e) {
            const float xv = xl[e];
            aR += xv * wR[e]; aZ += xv * wZ[e]; aN += xv * wN[e];
        }
        const float r = fsig(aR * mv + bihB[j] + bhhB[j]);
        const float z = fsig(aZ * mv + bihB[j + HH] + bhhB[j + HH]);
        const float n = ftanh(aN * mv + bihB[j + 2 * HH] + r * bhhB[j + 2 * HH]);
        zin[HH + j] = (1.f - z) * n;
    }
    __syncthreads();

    {
        float a = b1[j];
        const float* w = W1 + (size_t)j * (2 * HH + EMB);
        for (int i = 0; i < 2 * HH + EMB; ++i) a += zin[i] * w[i];
        l1[j] = fmaxf(a, 0.f);
    }
    __syncthreads();
    if (j < 64) {
        float a = b2[j];
        const float* w = W2 + (size_t)j * 128;
        for (int i = 0; i < 128; ++i) a += l1[i] * w[i];
        l2[j] = fmaxf(a, 0.f);
    }
    __syncthreads();
    if (j < 23) {
        float a = b3[j];
        const float* w = W3 + (size_t)j * 64;
        for (int i = 0; i < 64; ++i) a += l2[i] * w[i];
        out[b * 23 + j] = a;
    }
}

// ---------------------------------------------------------------------------
extern "C" void kernel_launch(void* const* d_in, const int* in_sizes, int n_in,
                              void* d_out, int out_size, void* d_ws, size_t ws_size,
                              hipStream_t stream) {
    const float* x     = (const float*)d_in[0];
    const float* mask  = (const float*)d_in[2];
    const float* Wih_f = (const float*)d_in[3];
    const float* Whh_f = (const float*)d_in[4];
    const float* bih_f = (const float*)d_in[5];
    const float* bhh_f = (const float*)d_in[6];
    const float* Wih_b = (const float*)d_in[7];
    const float* bih_b = (const float*)d_in[9];
    const float* bhh_b = (const float*)d_in[10];
    const float* W1 = (const float*)d_in[11];
    const float* b1 = (const float*)d_in[12];
    const float* W2 = (const float*)d_in[13];
    const float* b2 = (const float*)d_in[14];
    const float* W3 = (const float*)d_in[15];
    const float* b3 = (const float*)d_in[16];
    float* out = (float*)d_out;

    float* gi    = (float*)d_ws;                          // 64*1024*384 f32 = 96 MB
    float* spart = gi + (size_t)BS * SEQ * NG;            // 64*8*300
    float* hf    = spart + (size_t)BS * NCHUNK * EMB;     // 64*128

    gi_gemm<<<dim3(512), dim3(512), 0, stream>>>(x, mask, Wih_f, bih_f, bhh_f, gi);
    col_sum<<<dim3(BS, NCHUNK), dim3(320), 0, stream>>>(x, mask, spart);
    gru_scan<<<dim3(BS), dim3(256), 0, stream>>>(gi, Whh_f, bhh_f, hf);
    mlp<<<dim3(BS), dim3(128), 0, stream>>>(x, mask, Wih_b, bih_b, bhh_b, hf, spart,
                                            W1, b1, W2, b2, W3, b3, out);
}

// Round 14
// 540.853 us; speedup vs baseline: 1.1634x; 1.1634x over previous
//
#include <hip/hip_runtime.h>
#include <hip/hip_bf16.h>

#define HH   128
#define EMB  300
#define SEQ  1024
#define BS   64
#define NG   384   // 3*H
#define NCHUNK 8   // col_sum t-chunks

typedef __attribute__((ext_vector_type(8))) short  bf16x8;
typedef __attribute__((ext_vector_type(4))) float  f32x4;
typedef _Float16 f16x2 __attribute__((ext_vector_type(2)));

__device__ __forceinline__ unsigned short f2bf(float f) {
    unsigned int u = __float_as_uint(f);
    unsigned int r = (u + 0x7fffu + ((u >> 16) & 1u)) >> 16;   // RNE
    return (unsigned short)r;
}
__device__ __forceinline__ float fexp(float x) { return __builtin_amdgcn_exp2f(x * 1.44269504088896f); }
__device__ __forceinline__ float fsig(float x) { return __builtin_amdgcn_rcpf(1.f + fexp(-x)); }
__device__ __forceinline__ float ftanh(float x){ return __builtin_amdgcn_rcpf(1.f + fexp(-2.f*x)) * 2.f - 1.f; }

// sum over a 4-lane quad via two DPP quad_perm hops (pure VALU, no LDS).
__device__ __forceinline__ float dpp_quad_sum(float x) {
    int a = __builtin_amdgcn_mov_dpp(__float_as_int(x), 0xB1, 0xF, 0xF, true); // [1,0,3,2]
    float s = x + __int_as_float(a);
    int c = __builtin_amdgcn_mov_dpp(__float_as_int(s), 0x4E, 0xF, 0xF, true); // [2,3,0,1]
    return s + __int_as_float(c);
}

// LDS-only barrier: drains LDS ops but leaves global loads in flight.
#define BAR_LDS() asm volatile("s_waitcnt lgkmcnt(0)\n\ts_barrier" ::: "memory")

// ---------------------------------------------------------------------------
// gi[r, j] = (sum_e X[r,e]*mask[r]*W[j,e]) + bias[j] + (j<2H ? bhh[j] : 0)
// Single X pass: block = 128 M-rows x FULL N=384, 512 threads (8 waves 2m x 4n).
// ---------------------------------------------------------------------------
__global__ __launch_bounds__(512) void gi_gemm(const float* __restrict__ X,
                                               const float* __restrict__ mask,
                                               const float* __restrict__ W,
                                               const float* __restrict__ bias,
                                               const float* __restrict__ bhh2,
                                               float* __restrict__ out) {
    __shared__ __align__(16) unsigned short As[128 * 32];
    __shared__ __align__(16) unsigned short Bs[384 * 32];
    const int m0   = blockIdx.x * 128;
    const int tid  = threadIdx.x;
    const int row  = tid >> 2;            // 0..127
    const int seg  = tid & 3;             // 8-col segment
    const int wave = tid >> 6;            // 0..7
    const int lane = tid & 63;
    const int wm   = wave >> 2;           // 0..1 (64 M rows each)
    const int wn   = wave & 3;            // 0..3 (96 N cols each)
    const int r16  = lane & 15, kg = lane >> 4;

    f32x4 acc[4][6];
    #pragma unroll
    for (int m = 0; m < 4; ++m)
        #pragma unroll
        for (int n = 0; n < 6; ++n) acc[m][n] = (f32x4){0.f,0.f,0.f,0.f};

    const float mrow = mask[m0 + row];

    for (int k0 = 0; k0 < 320; k0 += 32) {
        // ---- stage A (x * mask -> bf16), 8 cols per thread ----
        {
            const float* src = X + (size_t)(m0 + row) * EMB + k0 + seg * 8;
            unsigned short tmp[8];
            if (k0 + seg * 8 + 7 < EMB) {
                float4 v0 = ((const float4*)src)[0];
                float4 v1 = ((const float4*)src)[1];
                tmp[0]=f2bf(v0.x*mrow); tmp[1]=f2bf(v0.y*mrow);
                tmp[2]=f2bf(v0.z*mrow); tmp[3]=f2bf(v0.w*mrow);
                tmp[4]=f2bf(v1.x*mrow); tmp[5]=f2bf(v1.y*mrow);
                tmp[6]=f2bf(v1.z*mrow); tmp[7]=f2bf(v1.w*mrow);
            } else {
                #pragma unroll
                for (int i = 0; i < 8; ++i) {
                    int c = k0 + seg * 8 + i;
                    float v = (c < EMB) ? src[i] : 0.f;
                    tmp[i] = f2bf(v * mrow);
                }
            }
            *(uint4*)&As[row * 32 + seg * 8] = *(const uint4*)tmp;
        }
        // ---- stage B (W -> bf16): 3 row-groups per thread ----
        #pragma unroll
        for (int r3 = 0; r3 < 3; ++r3) {
            const int rowb = row + r3 * 128;
            const float* src = W + (size_t)rowb * EMB + k0 + seg * 8;
            unsigned short tmp[8];
            if (k0 + seg * 8 + 7 < EMB) {
                float4 v0 = ((const float4*)src)[0];
                float4 v1 = ((const float4*)src)[1];
                tmp[0]=f2bf(v0.x); tmp[1]=f2bf(v0.y); tmp[2]=f2bf(v0.z); tmp[3]=f2bf(v0.w);
                tmp[4]=f2bf(v1.x); tmp[5]=f2bf(v1.y); tmp[6]=f2bf(v1.z); tmp[7]=f2bf(v1.w);
            } else {
                #pragma unroll
                for (int i = 0; i < 8; ++i) {
                    int c = k0 + seg * 8 + i;
                    float v = (c < EMB) ? src[i] : 0.f;
                    tmp[i] = f2bf(v);
                }
            }
            *(uint4*)&Bs[rowb * 32 + seg * 8] = *(const uint4*)tmp;
        }
        __syncthreads();

        bf16x8 a[4], bfr[6];
        #pragma unroll
        for (int m = 0; m < 4; ++m)
            a[m] = *(const bf16x8*)&As[(wm * 64 + m * 16 + r16) * 32 + kg * 8];
        #pragma unroll
        for (int n = 0; n < 6; ++n)
            bfr[n] = *(const bf16x8*)&Bs[(wn * 96 + n * 16 + r16) * 32 + kg * 8];
        #pragma unroll
        for (int m = 0; m < 4; ++m)
            #pragma unroll
            for (int n = 0; n < 6; ++n)
                acc[m][n] = __builtin_amdgcn_mfma_f32_16x16x32_bf16(a[m], bfr[n], acc[m][n], 0, 0, 0);
        __syncthreads();
    }

    // ---- epilogue: f32 gi with r/z recurrent bias folded ----
    #pragma unroll
    for (int m = 0; m < 4; ++m) {
        const int rowb = m0 + wm * 64 + m * 16 + kg * 4;
        #pragma unroll
        for (int n = 0; n < 6; ++n) {
            const int col = wn * 96 + n * 16 + r16;
            const float bj = bias[col] + (col < 2 * HH ? bhh2[col] : 0.f);
            #pragma unroll
            for (int q = 0; q < 4; ++q)
                out[(size_t)(rowb + q) * NG + col] = acc[m][n][q] + bj;
        }
    }
}

// ---------------------------------------------------------------------------
// partial column sums: spart[(b*NCHUNK + c)][e] = sum over 128 t's
// ---------------------------------------------------------------------------
__global__ __launch_bounds__(320) void col_sum(const float* __restrict__ X,
                                               const float* __restrict__ mask,
                                               float* __restrict__ spart) {
    const int b = blockIdx.x, c = blockIdx.y;
    const int e = threadIdx.x;
    if (e >= EMB) return;
    const int tchunk = SEQ / NCHUNK;   // 128
    float acc = 0.f;
    const float* xb = X + ((size_t)b * SEQ + (size_t)c * tchunk) * EMB;
    const float* mb = mask + (size_t)b * SEQ + (size_t)c * tchunk;
    for (int t = 0; t < tchunk; ++t)
        acc += xb[(size_t)t * EMB + e] * mb[t];
    spart[((size_t)b * NCHUNK + c) * EMB + e] = acc;
}

// ---------------------------------------------------------------------------
// forward GRU scan, g=6 decomposition: 256 threads, 64 blocks.
// Lane = (jj = tid>>2, k-quarter q = tid&3). Each lane computes dots for TWO
// outputs {jj, jj+64} over its 32-element k-slice (96 dot2/lane, same as r6)
// but reads only 64 B of h/step (HALF of r6's LDS delivery — the wave-shared
// LDS pipe was on the critical path). Full sums via 2-hop DPP quad reduce;
// each lane computes ONE gate-set (j = jj + (q>=2)*64, cndmask-selected).
// One barrier per step (double-buffered f16 h). gi f32 with r/z biases
// pre-folded; prefetched 4 steps ahead; BAR_LDS keeps loads in flight.
// ---------------------------------------------------------------------------
__global__ __launch_bounds__(256, 1) void gru_scan(const float* __restrict__ gi,
                                                   const float* __restrict__ Whh,
                                                   const float* __restrict__ bhh,
                                                   float* __restrict__ hout) {
    const int b   = blockIdx.x;
    const int tid = threadIdx.x;
    const int jj  = tid >> 2;                 // 0..63
    const int q   = tid & 3;                  // k-quarter
    const int jg  = jj + ((q >> 1) << 6);     // gate-owner output for this lane
    __shared__ __align__(16) _Float16 hb[2][HH];

    // ---- weights: rows {jj, jj+HH, jj+2HH} (A) and +64 (B), cols [q*32, q*32+32) ----
    f16x2 wAr[16], wAz[16], wAn[16], wBr[16], wBz[16], wBn[16];
    {
        const float2* a0 = (const float2*)(Whh + (size_t)jj * HH                 + q * 32);
        const float2* a1 = (const float2*)(Whh + (size_t)(jj + HH) * HH          + q * 32);
        const float2* a2 = (const float2*)(Whh + (size_t)(jj + 2 * HH) * HH      + q * 32);
        const float2* b0 = (const float2*)(Whh + (size_t)(jj + 64) * HH          + q * 32);
        const float2* b1 = (const float2*)(Whh + (size_t)(jj + 64 + HH) * HH     + q * 32);
        const float2* b2 = (const float2*)(Whh + (size_t)(jj + 64 + 2 * HH) * HH + q * 32);
        #pragma unroll
        for (int i = 0; i < 16; ++i) {
            float2 v;
            v = a0[i]; wAr[i] = (f16x2){(_Float16)v.x, (_Float16)v.y};
            v = a1[i]; wAz[i] = (f16x2){(_Float16)v.x, (_Float16)v.y};
            v = a2[i]; wAn[i] = (f16x2){(_Float16)v.x, (_Float16)v.y};
            v = b0[i]; wBr[i] = (f16x2){(_Float16)v.x, (_Float16)v.y};
            v = b1[i]; wBz[i] = (f16x2){(_Float16)v.x, (_Float16)v.y};
            v = b2[i]; wBn[i] = (f16x2){(_Float16)v.x, (_Float16)v.y};
        }
    }
    const float bn_ = bhh[jg + 2 * HH];   // r/z biases folded into gi
    const bool  ownA = (q < 2);

    float hreg = 0.f;
    if (tid < HH) hb[0][tid] = (_Float16)0.f;
    const float* gb = gi + (size_t)b * SEQ * NG;

    // depth-4 prefetch registers + incremental source pointers (row jg)
    float gAr, gAz, gAn, gBr, gBz, gBn, gCr, gCz, gCn, gDr, gDz, gDn;
    {
        const float* g0 = gb;               gAr = g0[jg]; gAz = g0[jg+HH]; gAn = g0[jg+2*HH];
        const float* g1 = gb + NG;          gBr = g1[jg]; gBz = g1[jg+HH]; gBn = g1[jg+2*HH];
        const float* g2 = gb + 2 * NG;      gCr = g2[jg]; gCz = g2[jg+HH]; gCn = g2[jg+2*HH];
        const float* g3 = gb + 3 * NG;      gDr = g3[jg]; gDz = g3[jg+HH]; gDn = g3[jg+2*HH];
    }
    const float* pA = gb + 4 * NG;
    const float* pB = gb + 5 * NG;
    const float* pC = gb + 6 * NG;
    const float* pD = gb + 7 * NG;
    BAR_LDS();

    // NOTE: prefetch in the final iterations reads past gi's end into the
    // spart/hf scratch regions (allocated) — loaded but never consumed.
#define GRU_BODY(P, GR, GZ, GN, PP)                                            \
    {                                                                          \
        float arA[2]={0.f,0.f}, azA[2]={0.f,0.f}, anA[2]={0.f,0.f};            \
        float arB[2]={0.f,0.f}, azB[2]={0.f,0.f}, anB[2]={0.f,0.f};            \
        const uint4* hp = (const uint4*)&hb[P][q * 32];                        \
        _Pragma("unroll")                                                      \
        for (int i = 0; i < 4; ++i) {                                          \
            union { uint4 u; f16x2 h2[4]; } U;                                 \
            U.u = hp[i];                                                       \
            _Pragma("unroll")                                                  \
            for (int k = 0; k < 4; ++k) {                                      \
                const int c = k & 1;                                           \
                arA[c] = __builtin_amdgcn_fdot2(wAr[i*4+k], U.h2[k], arA[c], false); \
                azA[c] = __builtin_amdgcn_fdot2(wAz[i*4+k], U.h2[k], azA[c], false); \
                anA[c] = __builtin_amdgcn_fdot2(wAn[i*4+k], U.h2[k], anA[c], false); \
                arB[c] = __builtin_amdgcn_fdot2(wBr[i*4+k], U.h2[k], arB[c], false); \
                azB[c] = __builtin_amdgcn_fdot2(wBz[i*4+k], U.h2[k], azB[c], false); \
                anB[c] = __builtin_amdgcn_fdot2(wBn[i*4+k], U.h2[k], anB[c], false); \
            }                                                                  \
        }                                                                      \
        const float sArf = dpp_quad_sum(arA[0] + arA[1]);                      \
        const float sAzf = dpp_quad_sum(azA[0] + azA[1]);                      \
        const float sAnf = dpp_quad_sum(anA[0] + anA[1]);                      \
        const float sBrf = dpp_quad_sum(arB[0] + arB[1]);                      \
        const float sBzf = dpp_quad_sum(azB[0] + azB[1]);                      \
        const float sBnf = dpp_quad_sum(anB[0] + anB[1]);                      \
        const float arf = ownA ? sArf : sBrf;                                  \
        const float azf = ownA ? sAzf : sBzf;                                  \
        const float anf = ownA ? sAnf : sBnf;                                  \
        const float r = fsig(GR + arf);                                        \
        const float z = fsig(GZ + azf);                                        \
        const float n = ftanh(GN + r * (anf + bn_));                           \
        hreg = n + z * (hreg - n);                                             \
        if (!(q & 1)) hb[P ^ 1][jg] = (_Float16)hreg;                          \
        GR = PP[jg]; GZ = PP[jg + HH]; GN = PP[jg + 2 * HH];                   \
        PP += 4 * NG;                                                          \
        BAR_LDS();                                                             \
    }

    for (int it = 0; it < SEQ / 4; ++it) {
        GRU_BODY(0, gAr, gAz, gAn, pA)
        GRU_BODY(1, gBr, gBz, gBn, pB)
        GRU_BODY(0, gCr, gCz, gCn, pC)
        GRU_BODY(1, gDr, gDz, gDn, pD)
    }
#undef GRU_BODY
    if (!(q & 1)) hout[b * HH + jg] = hreg;
}

// ---------------------------------------------------------------------------
// fused backward-direction GRU cell + MLP head.
// ---------------------------------------------------------------------------
__global__ __launch_bounds__(128) void mlp(const float* __restrict__ X,
                                           const float* __restrict__ mask,
                                           const float* __restrict__ WihB,
                                           const float* __restrict__ bihB,
                                           const float* __restrict__ bhhB,
                                           const float* __restrict__ hf,
                                           const float* __restrict__ spart,
                                           const float* __restrict__ W1, const float* __restrict__ b1,
                                           const float* __restrict__ W2, const float* __restrict__ b2,
                                           const float* __restrict__ W3, const float* __restrict__ b3,
                                           float* __restrict__ out) {
    const int b = blockIdx.x, j = threadIdx.x;
    __shared__ float xl[EMB];
    __shared__ float zin[2 * HH + EMB];   // 556
    __shared__ float l1[128];
    __shared__ float l2[64];

    const float* xr = X + ((size_t)b * SEQ + (SEQ - 1)) * EMB;
    const float  mv = mask[(size_t)b * SEQ + SEQ - 1];
    for (int e = j; e < EMB; e += 128) xl[e] = xr[e];
    zin[j] = hf[b * HH + j];
    for (int e = j; e < EMB; e += 128) {
        float v = 0.f;
        #pragma unroll
        for (int c = 0; c < NCHUNK; ++c)
            v += spart[((size_t)b * NCHUNK + c) * EMB + e];
        zin[2 * HH + e] = v * v;
    }
    __syncthreads();

    // ---- h_bwd[j]: one GRU cell on last token, h0 = 0 ----
    {
        const float* wR = WihB + (size_t)j * EMB;
        const float* wZ = WihB + (size_t)(j + HH) * EMB;
        const float* wN = WihB + (size_t)(j + 2 * HH) * EMB;
        float aR = 0.f, aZ = 0.f, aN = 0.f;
        for (int e = 0; e < EMB; ++e) {
            const float xv = xl[e];
            aR += xv * wR[e]; aZ += xv * wZ[e]; aN += xv * wN[e];
        }
        const float r = fsig(aR * mv + bihB[j] + bhhB[j]);
        const float z = fsig(aZ * mv + bihB[j + HH] + bhhB[j + HH]);
        const float n = ftanh(aN * mv + bihB[j + 2 * HH] + r * bhhB[j + 2 * HH]);
        zin[HH + j] = (1.f - z) * n;
    }
    __syncthreads();

    {
        float a = b1[j];
        const float* w = W1 + (size_t)j * (2 * HH + EMB);
        for (int i = 0; i < 2 * HH + EMB; ++i) a += zin[i] * w[i];
        l1[j] = fmaxf(a, 0.f);
    }
    __syncthreads();
    if (j < 64) {
        float a = b2[j];
        const float* w = W2 + (size_t)j * 128;
        for (int i = 0; i < 128; ++i) a += l1[i] * w[i];
        l2[j] = fmaxf(a, 0.f);
    }
    __syncthreads();
    if (j < 23) {
        float a = b3[j];
        const float* w = W3 + (size_t)j * 64;
        for (int i = 0; i < 64; ++i) a += l2[i] * w[i];
        out[b * 23 + j] = a;
    }
}

// ---------------------------------------------------------------------------
extern "C" void kernel_launch(void* const* d_in, const int* in_sizes, int n_in,
                              void* d_out, int out_size, void* d_ws, size_t ws_size,
                              hipStream_t stream) {
    const float* x     = (const float*)d_in[0];
    const float* mask  = (const float*)d_in[2];
    const float* Wih_f = (const float*)d_in[3];
    const float* Whh_f = (const float*)d_in[4];
    const float* bih_f = (const float*)d_in[5];
    const float* bhh_f = (const float*)d_in[6];
    const float* Wih_b = (const float*)d_in[7];
    const float* bih_b = (const float*)d_in[9];
    const float* bhh_b = (const float*)d_in[10];
    const float* W1 = (const float*)d_in[11];
    const float* b1 = (const float*)d_in[12];
    const float* W2 = (const float*)d_in[13];
    const float* b2 = (const float*)d_in[14];
    const float* W3 = (const float*)d_in[15];
    const float* b3 = (const float*)d_in[16];
    float* out = (float*)d_out;

    float* gi    = (float*)d_ws;                          // 64*1024*384 f32 = 96 MB
    float* spart = gi + (size_t)BS * SEQ * NG;            // 64*8*300
    float* hf    = spart + (size_t)BS * NCHUNK * EMB;     // 64*128

    gi_gemm<<<dim3(512), dim3(512), 0, stream>>>(x, mask, Wih_f, bih_f, bhh_f, gi);
    col_sum<<<dim3(BS, NCHUNK), dim3(320), 0, stream>>>(x, mask, spart);
    gru_scan<<<dim3(BS), dim3(256), 0, stream>>>(gi, Whh_f, bhh_f, hf);
    mlp<<<dim3(BS), dim3(128), 0, stream>>>(x, mask, Wih_b, bih_b, bhh_b, hf, spart,
                                            W1, b1, W2, b2, W3, b3, out);
}